// Round 1
// baseline (4174.151 us; speedup 1.0000x reference)
//
#include <hip/hip_runtime.h>
#include <stdint.h>

// RandomPropagate: 100 steps of jitter -> 3x3 maxpool -> coin mask -> goodness
// scale -> threshold commit, on a 2048x2048 f32 grid.
//
// PRNG: JAX threefry2x32, *partitionable* mode (default since jax 0.4.30):
//   fold_in(key, i)        = tf2x32(key, (0, i))            -> new key (o0,o1)
//   split(F)[j]            = tf2x32(F,   (0, j))            -> subkey (o0,o1)
//   random_bits32(key, p)  = o0 ^ o1 of tf2x32(key, (0, p)) (XOR fold)
//   uniform01(bits)        = bitcast((bits>>9)|0x3f800000) - 1.0f
// All f32 math uses _rn intrinsics to forbid FMA contraction (must match XLA's
// separate mul/add rounding).

#define HH 2048
#define WW 2048
#define NPIX (HH * WW)

// ---------- threefry2x32, exact JAX round structure ----------
__host__ __device__ __forceinline__ void tf2x32(uint32_t k0, uint32_t k1,
                                                uint32_t c0, uint32_t c1,
                                                uint32_t* o0, uint32_t* o1) {
  uint32_t ks2 = k0 ^ k1 ^ 0x1BD11BDAu;
  uint32_t x0 = c0 + k0, x1 = c1 + k1;
#define TFR(r) do { x0 += x1; x1 = (x1 << (r)) | (x1 >> (32 - (r))); x1 ^= x0; } while (0);
  TFR(13) TFR(15) TFR(26) TFR(6)
  x0 += k1; x1 += ks2 + 1u;
  TFR(17) TFR(29) TFR(16) TFR(24)
  x0 += ks2; x1 += k0 + 2u;
  TFR(13) TFR(15) TFR(26) TFR(6)
  x0 += k0; x1 += k1 + 3u;
  TFR(17) TFR(29) TFR(16) TFR(24)
  x0 += k1; x1 += ks2 + 4u;
  TFR(13) TFR(15) TFR(26) TFR(6)
  x0 += ks2; x1 += k0 + 5u;
#undef TFR
  *o0 = x0; *o1 = x1;
}

__device__ __forceinline__ float uniform01(uint32_t ka, uint32_t kb, uint32_t p) {
  uint32_t o0, o1;
  tf2x32(ka, kb, 0u, p, &o0, &o1);
  uint32_t bits = o0 ^ o1;  // partitionable 32-bit XOR fold
  return __uint_as_float((bits >> 9) | 0x3F800000u) - 1.0f;
}

// x0 = seed * habitat * goodness  (seed is exactly 0/1, so rounding is exact)
__global__ void k_init(const float* __restrict__ seed,
                       const float* __restrict__ hab,
                       const float* __restrict__ good,
                       float* __restrict__ x) {
  int p = blockIdx.x * blockDim.x + threadIdx.x;
  if (p >= NPIX) return;
  x[p] = __fmul_rn(__fmul_rn(seed[p], hab[p]), good[p]);
}

// t = x * (0.9999 + 1e-4 * U1)   -- separate mul/add rounding, no FMA
__global__ void k_jitter(const float* __restrict__ x,
                         float* __restrict__ t,
                         uint32_t ka, uint32_t kb) {
  int p = blockIdx.x * blockDim.x + threadIdx.x;
  if (p >= NPIX) return;
  float u = uniform01(ka, kb, (uint32_t)p);
  float s = __fadd_rn((float)(1.0 - 1e-4), __fmul_rn(1e-4f, u));
  t[p] = __fmul_rn(x[p], s);
}

// v = maxpool3x3(t) * (U2 > 0.5) * goodness ; x = (v - x > 0.05) ? v : x
// (y*(delta>THR) then max(y,x) collapses to this select since THR > 0, v >= 0)
__global__ void k_update(const float* __restrict__ t,
                         const float* __restrict__ good,
                         float* __restrict__ x,
                         uint32_t ka, uint32_t kb) {
  int p = blockIdx.x * blockDim.x + threadIdx.x;
  if (p >= NPIX) return;
  float u = uniform01(ka, kb, (uint32_t)p);
  float xv = x[p];
  float out = xv;
  if (u > 0.5f) {  // coin toss: mask multiply by exactly 1.0 -> v = M * goodness
    int r = p >> 11, c = p & (WW - 1);
    int r0 = r > 0 ? r - 1 : 0, r1 = r < HH - 1 ? r + 1 : HH - 1;
    int c0 = c > 0 ? c - 1 : 0, c1 = c < WW - 1 ? c + 1 : WW - 1;
    float m = -INFINITY;  // reduce_window init; all t >= 0 so clamp == -inf pad
    for (int rr = r0; rr <= r1; ++rr)
      for (int cc = c0; cc <= c1; ++cc)
        m = fmaxf(m, t[rr * WW + cc]);
    float v = __fmul_rn(m, good[p]);
    if (__fsub_rn(v, xv) > 0.05f) out = v;  // delta > THR commit
  }
  x[p] = out;
}

extern "C" void kernel_launch(void* const* d_in, const int* in_sizes, int n_in,
                              void* d_out, int out_size, void* d_ws, size_t ws_size,
                              hipStream_t stream) {
  const float* seed = (const float*)d_in[0];
  const float* hab  = (const float*)d_in[1];
  const float* good = (const float*)d_in[2];
  float* x = (float*)d_out;   // x lives in d_out the whole time
  float* t = (float*)d_ws;    // 16 MB jittered-field scratch

  dim3 blk(256), grd(NPIX / 256);
  k_init<<<grd, blk, 0, stream>>>(seed, hab, good, x);

  // sum(delta)==0.0 exactly (required for early exit) is unreachable once any
  // seed is nonzero: the coin toss gives delta = -x < 0 at ~half the covered
  // pixels. So the scan always runs all 100 steps.
  for (int i = 0; i < 100; ++i) {
    uint32_t f0, f1, a0, a1, b0, b1;
    tf2x32(0u, 42u, 0u, (uint32_t)i, &f0, &f1);  // fold_in(key(42), i)
    tf2x32(f0, f1, 0u, 0u, &a0, &a1);            // split -> k1 (jitter)
    tf2x32(f0, f1, 0u, 1u, &b0, &b1);            // split -> k2 (coin)
    k_jitter<<<grd, blk, 0, stream>>>(x, t, a0, a1);
    k_update<<<grd, blk, 0, stream>>>(t, good, x, b0, b1);
  }
}

// Round 2
// 2638.062 us; speedup vs baseline: 1.5823x; 1.5823x over previous
//
#include <hip/hip_runtime.h>
#include <stdint.h>

// RandomPropagate: 100 steps of jitter -> 3x3 maxpool -> coin mask -> goodness
// scale -> threshold commit, on a 2048x2048 f32 grid.
//
// Round 2: fully fused step kernel. Each block stages a 64x64 tile of the
// jittered field t (halo=1, 66x66 LDS, edge-clamped; duplication is
// max-idempotent == -inf pad) and commits 16 pixels/thread from LDS.
// x ping-pongs d_out <-> d_ws (100 even steps -> result ends in d_out).
//
// PRNG: JAX threefry2x32, partitionable mode (bit-exact vs reference, proven
// in round 1: absmax 0.0):
//   fold_in(key, i)       = tf2x32(key, (0, i))
//   split(F)[j]           = tf2x32(F,   (0, j))
//   random_bits32(key, p) = o0 ^ o1 of tf2x32(key, (0, p))
//   uniform01(bits)       = bitcast((bits>>9)|0x3f800000) - 1.0f
// All f32 math uses _rn intrinsics to forbid FMA contraction.

#define HH 2048
#define WW 2048
#define NPIX (HH * WW)
#define TS 64           // output tile side
#define PADW (TS + 2)   // 66, LDS row stride

// ---------- threefry2x32, exact JAX round structure ----------
__host__ __device__ __forceinline__ void tf2x32(uint32_t k0, uint32_t k1,
                                                uint32_t c0, uint32_t c1,
                                                uint32_t* o0, uint32_t* o1) {
  uint32_t ks2 = k0 ^ k1 ^ 0x1BD11BDAu;
  uint32_t x0 = c0 + k0, x1 = c1 + k1;
#define TFR(r) do { x0 += x1; x1 = (x1 << (r)) | (x1 >> (32 - (r))); x1 ^= x0; } while (0);
  TFR(13) TFR(15) TFR(26) TFR(6)
  x0 += k1; x1 += ks2 + 1u;
  TFR(17) TFR(29) TFR(16) TFR(24)
  x0 += ks2; x1 += k0 + 2u;
  TFR(13) TFR(15) TFR(26) TFR(6)
  x0 += k0; x1 += k1 + 3u;
  TFR(17) TFR(29) TFR(16) TFR(24)
  x0 += k1; x1 += ks2 + 4u;
  TFR(13) TFR(15) TFR(26) TFR(6)
  x0 += ks2; x1 += k0 + 5u;
#undef TFR
  *o0 = x0; *o1 = x1;
}

__device__ __forceinline__ float uniform01(uint32_t ka, uint32_t kb, uint32_t p) {
  uint32_t o0, o1;
  tf2x32(ka, kb, 0u, p, &o0, &o1);
  uint32_t bits = o0 ^ o1;  // partitionable 32-bit XOR fold
  return __uint_as_float((bits >> 9) | 0x3F800000u) - 1.0f;
}

// x0 = seed * habitat * goodness  (seed is exactly 0/1, so rounding is exact)
__global__ void k_init(const float* __restrict__ seed,
                       const float* __restrict__ hab,
                       const float* __restrict__ good,
                       float* __restrict__ x) {
  int p = blockIdx.x * blockDim.x + threadIdx.x;
  if (p >= NPIX) return;
  x[p] = __fmul_rn(__fmul_rn(seed[p], hab[p]), good[p]);
}

// One full step: t = x*(0.9999 + 1e-4*U1); v = maxpool3x3(t)*(U2>0.5)*good;
// x_out = (v - x > 0.05) ? v : x.
// (y*(delta>THR) then max(y,x) collapses to this select since THR>0, v>=0.)
__global__ __launch_bounds__(256) void k_step(const float* __restrict__ xin,
                                              const float* __restrict__ good,
                                              float* __restrict__ xout,
                                              uint32_t a0, uint32_t a1,
                                              uint32_t b0, uint32_t b1) {
  __shared__ float t[PADW * PADW];
  const int tid = threadIdx.x;
  const int r0 = blockIdx.y * TS;  // tile origin
  const int c0 = blockIdx.x * TS;

  // ---- stage jittered tile + halo (edge-clamped; clamp == -inf pad for max)
  for (int s = tid; s < PADW * PADW; s += 256) {
    int lr = s / PADW, lc = s - lr * PADW;
    int gr = r0 + lr - 1; gr = gr < 0 ? 0 : (gr > HH - 1 ? HH - 1 : gr);
    int gc = c0 + lc - 1; gc = gc < 0 ? 0 : (gc > WW - 1 ? WW - 1 : gc);
    int p = gr * WW + gc;
    float u = uniform01(a0, a1, (uint32_t)p);
    float s1 = __fadd_rn((float)(1.0 - 1e-4), __fmul_rn(1e-4f, u));
    t[s] = __fmul_rn(xin[p], s1);
  }
  __syncthreads();

  // ---- commit 16 pixels/thread: 4 rows x 64 cols per pass
  const int lc = tid & 63;        // local col 0..63
  const int lr0 = tid >> 6;       // local row base 0..3
#pragma unroll
  for (int j = 0; j < 16; ++j) {
    int lr = lr0 + 4 * j;
    int p = (r0 + lr) * WW + (c0 + lc);
    float u2 = uniform01(b0, b1, (uint32_t)p);
    float xv = xin[p];
    float out = xv;
    if (u2 > 0.5f) {  // coin pass: mask multiply is exactly 1.0
      const float* row = &t[(lr) * PADW + lc];  // (lr-1)+1 halo offset folded in
      float m = fmaxf(fmaxf(row[0], row[1]), row[2]);
      row += PADW;
      m = fmaxf(m, fmaxf(fmaxf(row[0], row[1]), row[2]));
      row += PADW;
      m = fmaxf(m, fmaxf(fmaxf(row[0], row[1]), row[2]));
      float v = __fmul_rn(m, good[p]);
      if (__fsub_rn(v, xv) > 0.05f) out = v;  // delta > THR commit
    }
    xout[p] = out;
  }
}

extern "C" void kernel_launch(void* const* d_in, const int* in_sizes, int n_in,
                              void* d_out, int out_size, void* d_ws, size_t ws_size,
                              hipStream_t stream) {
  const float* seed = (const float*)d_in[0];
  const float* hab  = (const float*)d_in[1];
  const float* good = (const float*)d_in[2];
  float* bufA = (float*)d_out;  // x starts and ends here (100 = even steps)
  float* bufB = (float*)d_ws;

  k_init<<<dim3(NPIX / 256), dim3(256), 0, stream>>>(seed, hab, good, bufA);

  // sum(delta)==0.0 exactly (required for early exit) is unreachable once any
  // seed is nonzero (coin toss gives delta = -x < 0 somewhere) -> all 100 steps.
  dim3 grd(WW / TS, HH / TS), blk(256);
  for (int i = 0; i < 100; ++i) {
    uint32_t f0, f1, a0, a1, b0, b1;
    tf2x32(0u, 42u, 0u, (uint32_t)i, &f0, &f1);  // fold_in(key(42), i)
    tf2x32(f0, f1, 0u, 0u, &a0, &a1);            // split -> k1 (jitter)
    tf2x32(f0, f1, 0u, 1u, &b0, &b1);            // split -> k2 (coin)
    const float* xin = (i & 1) ? bufB : bufA;
    float* xout      = (i & 1) ? bufA : bufB;
    k_step<<<grd, blk, 0, stream>>>(xin, good, xout, a0, a1, b0, b1);
  }
}

// Round 3
// 2117.999 us; speedup vs baseline: 1.9708x; 1.2455x over previous
//
#include <hip/hip_runtime.h>
#include <stdint.h>

// RandomPropagate: 100 steps of jitter -> 3x3 maxpool -> coin mask -> goodness
// scale -> threshold commit, on a 2048x2048 f32 grid.
//
// Round 3: value-gated RNG. Threefry is ~70% of step cycles; both draws are
// skippable without changing any consumed bit:
//   - jitter draw needed only where x != 0    (t = 0 * s == +0 exactly)
//   - coin draw needed only where v - x > THR (reordered: maxpool -> v -> gate
//     -> draw; per-pixel counter streams make skipped draws side-effect free)
//   - all-zero staged tile -> output tile is exactly 0, write zeros & return
// x ping-pongs d_out <-> d_ws (100 even steps -> result ends in d_out).
//
// PRNG: JAX threefry2x32, partitionable mode (bit-exact, absmax 0.0 in R1/R2):
//   fold_in(key, i)       = tf2x32(key, (0, i))
//   split(F)[j]           = tf2x32(F,   (0, j))
//   random_bits32(key, p) = o0 ^ o1 of tf2x32(key, (0, p))
//   uniform01(bits)       = bitcast((bits>>9)|0x3f800000) - 1.0f
// All f32 math uses _rn intrinsics to forbid FMA contraction.

#define HH 2048
#define WW 2048
#define NPIX (HH * WW)
#define TS 64           // output tile side
#define PADW (TS + 2)   // 66, LDS row stride

// ---------- threefry2x32, exact JAX round structure ----------
__host__ __device__ __forceinline__ void tf2x32(uint32_t k0, uint32_t k1,
                                                uint32_t c0, uint32_t c1,
                                                uint32_t* o0, uint32_t* o1) {
  uint32_t ks2 = k0 ^ k1 ^ 0x1BD11BDAu;
  uint32_t x0 = c0 + k0, x1 = c1 + k1;
#define TFR(r) do { x0 += x1; x1 = (x1 << (r)) | (x1 >> (32 - (r))); x1 ^= x0; } while (0);
  TFR(13) TFR(15) TFR(26) TFR(6)
  x0 += k1; x1 += ks2 + 1u;
  TFR(17) TFR(29) TFR(16) TFR(24)
  x0 += ks2; x1 += k0 + 2u;
  TFR(13) TFR(15) TFR(26) TFR(6)
  x0 += k0; x1 += k1 + 3u;
  TFR(17) TFR(29) TFR(16) TFR(24)
  x0 += k1; x1 += ks2 + 4u;
  TFR(13) TFR(15) TFR(26) TFR(6)
  x0 += ks2; x1 += k0 + 5u;
#undef TFR
  *o0 = x0; *o1 = x1;
}

__device__ __forceinline__ float uniform01(uint32_t ka, uint32_t kb, uint32_t p) {
  uint32_t o0, o1;
  tf2x32(ka, kb, 0u, p, &o0, &o1);
  uint32_t bits = o0 ^ o1;  // partitionable 32-bit XOR fold
  return __uint_as_float((bits >> 9) | 0x3F800000u) - 1.0f;
}

// x0 = seed * habitat * goodness  (seed is exactly 0/1, so rounding is exact)
__global__ void k_init(const float* __restrict__ seed,
                       const float* __restrict__ hab,
                       const float* __restrict__ good,
                       float* __restrict__ x) {
  int p = blockIdx.x * blockDim.x + threadIdx.x;
  if (p >= NPIX) return;
  x[p] = __fmul_rn(__fmul_rn(seed[p], hab[p]), good[p]);
}

// One full step: t = x*(0.9999 + 1e-4*U1); v = maxpool3x3(t)*(U2>0.5)*good;
// x_out = (v - x > 0.05) ? v : x.
// Exact reorder of the reference dataflow:
//   u2<=0.5 : y3=0, delta=-x<=0 -> out=x      (no v needed)
//   u2>0.5  : v=m*good; out = (v-x>THR) ? v : x
// => out=x unless (v-x>THR && u2>0.5); draw u2 only when v-x>THR.
__global__ __launch_bounds__(256) void k_step(const float* __restrict__ xin,
                                              const float* __restrict__ good,
                                              float* __restrict__ xout,
                                              uint32_t a0, uint32_t a1,
                                              uint32_t b0, uint32_t b1) {
  __shared__ float t[PADW * PADW];
  __shared__ int any_nz;
  const int tid = threadIdx.x;
  const int r0 = blockIdx.y * TS;  // tile origin
  const int c0 = blockIdx.x * TS;

  if (tid == 0) any_nz = 0;
  __syncthreads();

  // ---- stage jittered tile + halo (edge-clamped; clamp == -inf pad for max)
  int my_nz = 0;
  for (int s = tid; s < PADW * PADW; s += 256) {
    int lr = s / PADW, lc = s - lr * PADW;
    int gr = r0 + lr - 1; gr = gr < 0 ? 0 : (gr > HH - 1 ? HH - 1 : gr);
    int gc = c0 + lc - 1; gc = gc < 0 ? 0 : (gc > WW - 1 ? WW - 1 : gc);
    int p = gr * WW + gc;
    float xv = xin[p];
    float tv = 0.0f;
    if (xv != 0.0f) {  // jitter draw only where x != 0 (0*s == +0 exactly)
      my_nz = 1;
      float u = uniform01(a0, a1, (uint32_t)p);
      float s1 = __fadd_rn((float)(1.0 - 1e-4), __fmul_rn(1e-4f, u));
      tv = __fmul_rn(xv, s1);
    }
    t[s] = tv;
  }
  if (my_nz) any_nz = 1;  // benign race: all writers store 1
  __syncthreads();

  // ---- all-zero staged region: entire output tile is exactly 0
  if (!any_nz) {
    const int lc = tid & 63, lr0 = tid >> 6;
#pragma unroll
    for (int j = 0; j < 16; ++j)
      xout[(r0 + lr0 + 4 * j) * WW + (c0 + lc)] = 0.0f;
    return;
  }

  // ---- commit 16 pixels/thread: one 64-wide row per wave (coherent gating)
  const int lc = tid & 63;        // local col 0..63
  const int lr0 = tid >> 6;       // local row base 0..3
#pragma unroll
  for (int j = 0; j < 16; ++j) {
    int lr = lr0 + 4 * j;
    int p = (r0 + lr) * WW + (c0 + lc);
    float xv = xin[p];
    float out = xv;
    const float* row = &t[lr * PADW + lc];  // (lr-1)+1 halo offset folded in
    float m = fmaxf(fmaxf(row[0], row[1]), row[2]);
    row += PADW;
    m = fmaxf(m, fmaxf(fmaxf(row[0], row[1]), row[2]));
    row += PADW;
    m = fmaxf(m, fmaxf(fmaxf(row[0], row[1]), row[2]));
    if (m > 0.0f) {                       // v==0 can never beat xv + THR
      float v = __fmul_rn(m, good[p]);
      if (__fsub_rn(v, xv) > 0.05f) {     // commit possible -> coin draw
        float u2 = uniform01(b0, b1, (uint32_t)p);
        if (u2 > 0.5f) out = v;
      }
    }
    xout[p] = out;
  }
}

extern "C" void kernel_launch(void* const* d_in, const int* in_sizes, int n_in,
                              void* d_out, int out_size, void* d_ws, size_t ws_size,
                              hipStream_t stream) {
  const float* seed = (const float*)d_in[0];
  const float* hab  = (const float*)d_in[1];
  const float* good = (const float*)d_in[2];
  float* bufA = (float*)d_out;  // x starts and ends here (100 = even steps)
  float* bufB = (float*)d_ws;

  k_init<<<dim3(NPIX / 256), dim3(256), 0, stream>>>(seed, hab, good, bufA);

  // sum(delta)==0.0 exactly (required for early exit) is unreachable once any
  // seed is nonzero (coin toss gives delta = -x < 0 somewhere) -> all 100 steps.
  dim3 grd(WW / TS, HH / TS), blk(256);
  for (int i = 0; i < 100; ++i) {
    uint32_t f0, f1, a0, a1, b0, b1;
    tf2x32(0u, 42u, 0u, (uint32_t)i, &f0, &f1);  // fold_in(key(42), i)
    tf2x32(f0, f1, 0u, 0u, &a0, &a1);            // split -> k1 (jitter)
    tf2x32(f0, f1, 0u, 1u, &b0, &b1);            // split -> k2 (coin)
    const float* xin = (i & 1) ? bufB : bufA;
    float* xout      = (i & 1) ? bufA : bufB;
    k_step<<<grd, blk, 0, stream>>>(xin, good, xout, a0, a1, b0, b1);
  }
}